// Round 2
// baseline (276.278 us; speedup 1.0000x reference)
//
#include <hip/hip_runtime.h>

// Squared Euclidean distance: out[i][j] = ||a_i||^2 + ||b_j||^2 - 2 a_i.b_j
// a: [8192,128] fp32, b: [8192,128] fp32, out: [8192,8192] fp32.
//
// v3 strategy (= v2 + ws_size guard):
//   FAST PATH (needs ~4.25 MiB workspace):
//     prep_kernel: exact fp32 row norms + ONE-TIME fp32->bf16 conversion of
//                  both matrices into d_ws.
//     dist_kernel: K=128 single-stage bf16 MFMA GEMM. Staging via
//                  global_load_lds width=16 (no VALU, no reg round-trip).
//                  LDS rows are 256B stride -> XOR-swizzle (byte ^= (row&7)<<4)
//                  applied on BOTH sides (pre-swizzled global source +
//                  swizzled ds_read) to kill 16-way bank conflicts.
//   FALLBACK (ws too small): round-0 kernel verbatim (convert-in-kernel,
//     needs only 64 KiB ws; known-good at ~275 us).
// Write-bound floor: 256 MiB out @6.3TB/s => ~43us for dist_kernel.

typedef __attribute__((ext_vector_type(8))) short bf16x8;   // 8 bf16 = 4 VGPRs
typedef __attribute__((ext_vector_type(4))) float f32x4;    // MFMA acc

// fp32 -> bf16 round-to-nearest-even
__device__ __forceinline__ unsigned short f2bf(float f) {
    union { float f; unsigned u; } x; x.f = f;
    unsigned r = x.u + 0x7FFFu + ((x.u >> 16) & 1u);
    return (unsigned short)(r >> 16);
}

// ---------------- kernel 1: norms (+ optional bf16 convert) ----------------
// one wave (64 lanes) per row of 128 floats.
__global__ void prep_kernel(const float* __restrict__ m1,
                            const float* __restrict__ m2,
                            float* __restrict__ n1,
                            float* __restrict__ n2,
                            unsigned short* __restrict__ abf,
                            unsigned short* __restrict__ bbf,
                            int rows1, int rows2) {
    int gwave = (int)((blockIdx.x * blockDim.x + threadIdx.x) >> 6);
    int lane  = threadIdx.x & 63;
    const float* src;
    float* ndst;
    unsigned short* bdst;
    int row;
    if (gwave < rows1) { src = m1; ndst = n1; bdst = abf; row = gwave; }
    else {
        row = gwave - rows1;
        if (row >= rows2) return;
        src = m2; ndst = n2; bdst = bbf;
    }
    const float2* p = (const float2*)(src + (size_t)row * 128);
    float2 v = p[lane];
    float s = v.x * v.x + v.y * v.y;
    if (bdst) {
        ushort2 w;
        w.x = f2bf(v.x);
        w.y = f2bf(v.y);
        *(ushort2*)(bdst + (size_t)row * 128 + lane * 2) = w;
    }
#pragma unroll
    for (int off = 32; off; off >>= 1) s += __shfl_xor(s, off, 64);
    if (lane == 0) ndst[row] = s;
}

// ---------------- kernel 2 (fast): bf16 MFMA cross-term + epilogue ----------
#define BM 128
#define BN 128
// full K = 128 staged at once: As 128x128 bf16 = 32 KiB, Bs 32 KiB.

__global__ __launch_bounds__(256, 2)
void dist_kernel(const unsigned short* __restrict__ Abf,
                 const unsigned short* __restrict__ Bbf,
                 const float* __restrict__ n1, const float* __restrict__ n2,
                 float* __restrict__ out, int N2) {
    __shared__ char lds[65536];            // [0,32K) = A tile, [32K,64K) = B tile

    const int tid  = threadIdx.x;
    const int wave = tid >> 6;             // 0..3
    const int lane = tid & 63;
    const int q    = lane >> 4;            // quad 0..3
    const int l15  = lane & 15;

    const int ti = blockIdx.y * BM;        // rows of mat1
    const int tj = blockIdx.x * BN;        // rows of mat2 (= cols of out)

    // ---- stage A and B tiles: global_load_lds, 16B/lane, pre-swizzled src ----
    // LDS is written LINEARLY (wave-uniform base + lane*16, rule #21); the
    // global source address carries the inverse XOR swizzle so that a read of
    // LDS[row*256 + (c ^ ((row&7)<<4))] returns element (row, c).
    {
        const char* Ab = (const char*)Abf + (size_t)ti * 256;
        const char* Bb = (const char*)Bbf + (size_t)tj * 256;
        const int rl = wave * 4 + (lane >> 4);   // row within a 16-row group
        const int c  = (lane & 15) * 16;         // byte col, 16B aligned
#pragma unroll
        for (int it = 0; it < 8; ++it) {
            int row = it * 16 + rl;              // 0..127
            int sc  = c ^ ((row & 7) << 4);
            __builtin_amdgcn_global_load_lds(
                (const __attribute__((address_space(1))) void*)(Ab + (size_t)row * 256 + sc),
                (__attribute__((address_space(3))) void*)(lds + it * 4096 + wave * 1024),
                16, 0, 0);
        }
#pragma unroll
        for (int it = 0; it < 8; ++it) {
            int row = it * 16 + rl;
            int sc  = c ^ ((row & 7) << 4);
            __builtin_amdgcn_global_load_lds(
                (const __attribute__((address_space(1))) void*)(Bb + (size_t)row * 256 + sc),
                (__attribute__((address_space(3))) void*)(lds + 32768 + it * 4096 + wave * 1024),
                16, 0, 0);
        }
    }
    __syncthreads();

    const int wm = (wave >> 1) * 64;       // wave's 64x64 sub-tile
    const int wn = (wave & 1) * 64;

    f32x4 acc[4][4] = {};                  // zero-init

    // ---- MFMA over K=128 ----
    // A frag: lane holds A[m = l15][k = q*8+j]; B frag: B[k = q*8+j][n = l15]
    const char* Abase = lds;
    const char* Bbase = lds + 32768;
#pragma unroll
    for (int kk = 0; kk < 128; kk += 32) {
        const int cb = kk * 2 + q * 16;    // byte col of this lane's 8 bf16
        bf16x8 af[4], bfr[4];
#pragma unroll
        for (int mi = 0; mi < 4; ++mi) {
            int row = wm + mi * 16 + l15;
            af[mi] = *(const bf16x8*)(Abase + row * 256 + (cb ^ ((row & 7) << 4)));
        }
#pragma unroll
        for (int ni = 0; ni < 4; ++ni) {
            int row = wn + ni * 16 + l15;
            bfr[ni] = *(const bf16x8*)(Bbase + row * 256 + (cb ^ ((row & 7) << 4)));
        }
#pragma unroll
        for (int mi = 0; mi < 4; ++mi)
#pragma unroll
            for (int ni = 0; ni < 4; ++ni)
                acc[mi][ni] = __builtin_amdgcn_mfma_f32_16x16x32_bf16(
                    af[mi], bfr[ni], acc[mi][ni], 0, 0, 0);
    }

    // ---- epilogue: out = n1[r] + n2[c] - 2*cross ----
    // C/D layout: col = l15, row = q*4 + reg  (verified m89/m91)
#pragma unroll
    for (int mi = 0; mi < 4; ++mi) {
        int r0 = ti + wm + mi * 16 + q * 4;
        float a0 = n1[r0 + 0], a1 = n1[r0 + 1], a2 = n1[r0 + 2], a3 = n1[r0 + 3];
#pragma unroll
        for (int ni = 0; ni < 4; ++ni) {
            int c = tj + wn + ni * 16 + l15;
            float nb = n2[c];
            f32x4 v = acc[mi][ni];
            out[(size_t)(r0 + 0) * N2 + c] = a0 + nb - 2.0f * v[0];
            out[(size_t)(r0 + 1) * N2 + c] = a1 + nb - 2.0f * v[1];
            out[(size_t)(r0 + 2) * N2 + c] = a2 + nb - 2.0f * v[2];
            out[(size_t)(r0 + 3) * N2 + c] = a3 + nb - 2.0f * v[3];
        }
    }
}

// ---------------- kernel 2 (fallback): round-0 kernel verbatim --------------
// Convert-in-kernel, 2x BK=64 chunks. Needs only n1/n2 in workspace.
__global__ __launch_bounds__(256, 3)
void dist_kernel_fb(const float* __restrict__ A, const float* __restrict__ B,
                    const float* __restrict__ n1, const float* __restrict__ n2,
                    float* __restrict__ out, int N2) {
    __shared__ short As[128][64];
    __shared__ short Bs[128][64];

    const int tid  = threadIdx.x;
    const int wave = tid >> 6;
    const int lane = tid & 63;
    const int q    = lane >> 4;
    const int l15  = lane & 15;

    const int ti = blockIdx.y * 128;
    const int tj = blockIdx.x * 128;

    const int wm = (wave >> 1) * 64;
    const int wn = (wave & 1) * 64;

    f32x4 acc[4][4] = {};

    for (int kc = 0; kc < 128; kc += 64) {
#pragma unroll
        for (int g = 0; g < 4; ++g) {
            int idx = tid + g * 256;
            int row = idx >> 3;
            int kg  = (idx & 7) * 8;
            const float4* pa = (const float4*)(A + (size_t)(ti + row) * 128 + kc + kg);
            float4 v0 = pa[0], v1 = pa[1];
            bf16x8 w;
            w[0] = f2bf(v0.x); w[1] = f2bf(v0.y); w[2] = f2bf(v0.z); w[3] = f2bf(v0.w);
            w[4] = f2bf(v1.x); w[5] = f2bf(v1.y); w[6] = f2bf(v1.z); w[7] = f2bf(v1.w);
            *(bf16x8*)&As[row][kg] = w;
        }
#pragma unroll
        for (int g = 0; g < 4; ++g) {
            int idx = tid + g * 256;
            int row = idx >> 3;
            int kg  = (idx & 7) * 8;
            const float4* pb = (const float4*)(B + (size_t)(tj + row) * 128 + kc + kg);
            float4 v0 = pb[0], v1 = pb[1];
            bf16x8 w;
            w[0] = f2bf(v0.x); w[1] = f2bf(v0.y); w[2] = f2bf(v0.z); w[3] = f2bf(v0.w);
            w[4] = f2bf(v1.x); w[5] = f2bf(v1.y); w[6] = f2bf(v1.z); w[7] = f2bf(v1.w);
            *(bf16x8*)&Bs[row][kg] = w;
        }
        __syncthreads();

#pragma unroll
        for (int kk = 0; kk < 64; kk += 32) {
            bf16x8 af[4], bfr[4];
#pragma unroll
            for (int mi = 0; mi < 4; ++mi)
                af[mi] = *(const bf16x8*)&As[wm + mi * 16 + l15][kk + q * 8];
#pragma unroll
            for (int ni = 0; ni < 4; ++ni)
                bfr[ni] = *(const bf16x8*)&Bs[wn + ni * 16 + l15][kk + q * 8];
#pragma unroll
            for (int mi = 0; mi < 4; ++mi)
#pragma unroll
                for (int ni = 0; ni < 4; ++ni)
                    acc[mi][ni] = __builtin_amdgcn_mfma_f32_16x16x32_bf16(
                        af[mi], bfr[ni], acc[mi][ni], 0, 0, 0);
        }
        __syncthreads();
    }

#pragma unroll
    for (int mi = 0; mi < 4; ++mi) {
        int r0 = ti + wm + mi * 16 + q * 4;
        float a0 = n1[r0 + 0], a1 = n1[r0 + 1], a2 = n1[r0 + 2], a3 = n1[r0 + 3];
#pragma unroll
        for (int ni = 0; ni < 4; ++ni) {
            int c = tj + wn + ni * 16 + l15;
            float nb = n2[c];
            f32x4 v = acc[mi][ni];
            out[(size_t)(r0 + 0) * N2 + c] = a0 + nb - 2.0f * v[0];
            out[(size_t)(r0 + 1) * N2 + c] = a1 + nb - 2.0f * v[1];
            out[(size_t)(r0 + 2) * N2 + c] = a2 + nb - 2.0f * v[2];
            out[(size_t)(r0 + 3) * N2 + c] = a3 + nb - 2.0f * v[3];
        }
    }
}

extern "C" void kernel_launch(void* const* d_in, const int* in_sizes, int n_in,
                              void* d_out, int out_size, void* d_ws, size_t ws_size,
                              hipStream_t stream) {
    const float* m1 = (const float*)d_in[0];
    const float* m2 = (const float*)d_in[1];
    float* out = (float*)d_out;
    const int rows1 = in_sizes[0] / 128;   // 8192
    const int rows2 = in_sizes[1] / 128;   // 8192

    // workspace layout: n1 | n2 | Abf (bf16) | Bbf (bf16)
    const size_t need_norms = (size_t)(rows1 + rows2) * sizeof(float);
    const size_t need_bf16  = (size_t)(rows1 + rows2) * 128 * sizeof(unsigned short);
    const bool   fast       = ws_size >= need_norms + need_bf16;

    float* n1 = (float*)d_ws;
    float* n2 = n1 + rows1;
    unsigned short* abf = fast ? (unsigned short*)(n2 + rows2) : nullptr;
    unsigned short* bbf = fast ? abf + (size_t)rows1 * 128 : nullptr;

    int total_waves = rows1 + rows2;
    int nb = (total_waves * 64 + 255) / 256;
    prep_kernel<<<nb, 256, 0, stream>>>(m1, m2, n1, n2, abf, bbf, rows1, rows2);

    dim3 grid(rows2 / BN, rows1 / BM);
    if (fast)
        dist_kernel<<<grid, 256, 0, stream>>>(abf, bbf, n1, n2, out, rows2);
    else
        dist_kernel_fb<<<grid, 256, 0, stream>>>(m1, m2, n1, n2, out, rows2);
}